// Round 1
// baseline (112.359 us; speedup 1.0000x reference)
//
#include <hip/hip_runtime.h>
#include <math.h>

// LengthRegulator: B=16, T=512, D=512, T_OUT=2560, all float32.
// Stage 1: per-batch inclusive cumsum of round(dur) -> ends[B][T] (in d_ws).
// Stage 2: per output frame j, src = first t with ends[t] > j (binary search,
//          block-uniform), copy x[b,src,:] as float4s; zeros past total length.

#define LR_B 16
#define LR_T 512
#define LR_D 512
#define LR_TOUT 2560

__global__ void lr_scan_kernel(const float* __restrict__ dur, int* __restrict__ ends) {
    const int b = blockIdx.x;
    const int t = threadIdx.x;
    __shared__ int s[LR_T];
    float dv = dur[b * LR_T + t];
    s[t] = (int)floorf(dv + 0.5f);
    __syncthreads();
    // Hillis-Steele inclusive scan over 512 elements
    #pragma unroll
    for (int off = 1; off < LR_T; off <<= 1) {
        int v = (t >= off) ? s[t - off] : 0;
        __syncthreads();
        s[t] += v;
        __syncthreads();
    }
    ends[b * LR_T + t] = s[t];
}

__global__ void lr_expand_kernel(const float* __restrict__ x,
                                 const int* __restrict__ ends,
                                 float* __restrict__ out) {
    const int j = blockIdx.x;      // output frame [0, T_OUT)
    const int b = blockIdx.y;      // batch
    const int tid = threadIdx.x;   // 128 threads, each moves a float4 (D=512)

    const int* e = ends + b * LR_T;
    const int total = e[LR_T - 1];

    float4 val = make_float4(0.f, 0.f, 0.f, 0.f);
    if (j < total) {
        // first t with e[t] > j  (searchsorted side='right'); block-uniform
        int lo = 0, hi = LR_T;
        while (lo < hi) {
            int mid = (lo + hi) >> 1;
            if (e[mid] > j) hi = mid; else lo = mid + 1;
        }
        int src = (lo < LR_T - 1) ? lo : (LR_T - 1);
        const float4* row = (const float4*)(x + (size_t)(b * LR_T + src) * LR_D);
        val = row[tid];
    }
    float4* orow = (float4*)(out + (size_t)(b * LR_TOUT + j) * LR_D);
    orow[tid] = val;
}

extern "C" void kernel_launch(void* const* d_in, const int* in_sizes, int n_in,
                              void* d_out, int out_size, void* d_ws, size_t ws_size,
                              hipStream_t stream) {
    const float* x   = (const float*)d_in[0];   // [B, T, D] f32
    const float* dur = (const float*)d_in[1];   // [B, T]    f32
    float* out = (float*)d_out;                 // [B, T_OUT, D] f32
    int* ends = (int*)d_ws;                     // B*T ints = 32 KB scratch

    lr_scan_kernel<<<LR_B, LR_T, 0, stream>>>(dur, ends);

    dim3 grid(LR_TOUT, LR_B);
    lr_expand_kernel<<<grid, 128, 0, stream>>>(x, ends, out);
}

// Round 3
// 107.131 us; speedup vs baseline: 1.0488x; 1.0488x over previous
//
#include <hip/hip_runtime.h>
#include <math.h>

// LengthRegulator: B=16, T=512, D=512, T_OUT=2560, all float32.
// Stage 1 (16 blocks x 512 thr): per-batch inclusive cumsum of round(dur) in
//   LDS, then binary-search ALL T_OUT positions -> src[b][j] table in d_ws
//   (-1 = past total length). Removes the dependent-load search chain from
//   the bandwidth kernel.
// Stage 2 (1280x16 blocks x 256 thr): each 128-thread half-block copies one
//   output frame: 1 src load -> 1 float4 x load -> float4 store. Pure BW.

#define LR_B 16
#define LR_T 512
#define LR_D 512
#define LR_TOUT 2560

__global__ void lr_prep_kernel(const float* __restrict__ dur, int* __restrict__ src) {
    const int b = blockIdx.x;
    const int t = threadIdx.x;          // 512 threads
    __shared__ int s[LR_T];
    float dv = dur[b * LR_T + t];
    s[t] = (int)floorf(dv + 0.5f);
    __syncthreads();
    // Hillis-Steele inclusive scan over 512 elements
    #pragma unroll
    for (int off = 1; off < LR_T; off <<= 1) {
        int v = (t >= off) ? s[t - off] : 0;
        __syncthreads();
        s[t] += v;
        __syncthreads();
    }
    const int total = s[LR_T - 1];
    // Each thread resolves 5 output positions (2560 = 5 * 512).
    #pragma unroll
    for (int k = 0; k < LR_TOUT / LR_T; ++k) {
        const int j = t + k * LR_T;
        int v;
        if (j < total) {
            // first idx with s[idx] > j  (searchsorted side='right').
            // Interval starts at 512 -> needs 10 halvings to reach size 0.
            int lo = 0, hi = LR_T;
            #pragma unroll
            for (int it = 0; it < 10; ++it) {
                if (lo < hi) {
                    int mid = (lo + hi) >> 1;
                    if (s[mid] > j) hi = mid; else lo = mid + 1;
                }
            }
            v = (lo < LR_T - 1) ? lo : (LR_T - 1);
        } else {
            v = -1;
        }
        src[b * LR_TOUT + j] = v;
    }
}

__global__ void lr_expand_kernel(const float* __restrict__ x,
                                 const int* __restrict__ src,
                                 float* __restrict__ out) {
    const int b = blockIdx.y;
    const int j = blockIdx.x * 2 + (threadIdx.x >> 7);  // output frame
    const int lane = threadIdx.x & 127;                 // float4 slot within row

    const int si = src[b * LR_TOUT + j];   // uniform across the 128 threads
    float4 val = make_float4(0.f, 0.f, 0.f, 0.f);
    if (si >= 0) {
        const float4* row = (const float4*)(x + (size_t)(b * LR_T + si) * LR_D);
        val = row[lane];
    }
    float4* orow = (float4*)(out + (size_t)(b * LR_TOUT + j) * LR_D);
    orow[lane] = val;
}

extern "C" void kernel_launch(void* const* d_in, const int* in_sizes, int n_in,
                              void* d_out, int out_size, void* d_ws, size_t ws_size,
                              hipStream_t stream) {
    const float* x   = (const float*)d_in[0];   // [B, T, D] f32
    const float* dur = (const float*)d_in[1];   // [B, T]    f32
    float* out = (float*)d_out;                 // [B, T_OUT, D] f32
    int* src = (int*)d_ws;                      // B*T_OUT ints = 160 KB scratch

    lr_prep_kernel<<<LR_B, LR_T, 0, stream>>>(dur, src);

    dim3 grid(LR_TOUT / 2, LR_B);
    lr_expand_kernel<<<grid, 256, 0, stream>>>(x, src, out);
}

// Round 4
// 101.798 us; speedup vs baseline: 1.1037x; 1.0524x over previous
//
#include <hip/hip_runtime.h>
#include <math.h>

// LengthRegulator: B=16, T=512, D=512, T_OUT=2560, all float32. Fully fused:
// ONE kernel, grid (T_OUT/16, B) x 512 threads. Each block is self-contained:
//   1. coalesced load of its batch's 512 durations (2 KB, L2-hot),
//   2. hybrid scan: wave-shuffle inclusive scan (6 shfl_up, no barriers) +
//      8-wave LDS combine -> full ends[] in LDS (3 barriers total vs 18 for
//      Hillis-Steele),
//   3. threads 0..15 binary-search the block's 16 output frames -> src16[],
//   4. 4 unrolled copy passes: 512 threads x float4 = 4 frames/pass,
//      8 KB contiguous stores per pass. Zeros past total length.
// Replicated scan cost across the grid ~1-2 us of VALU; buys: one launch,
// no prep kernel (which used 16 of 256 CUs), no src-table round trip, no
// inter-kernel bubble.

#define LR_B 16
#define LR_T 512
#define LR_D 512
#define LR_TOUT 2560
#define FRAMES_PER_BLOCK 16

__global__ __launch_bounds__(512) void lr_fused_kernel(
        const float* __restrict__ x,
        const float* __restrict__ dur,
        float* __restrict__ out) {
    const int b    = blockIdx.y;
    const int base = blockIdx.x * FRAMES_PER_BLOCK;
    const int tid  = threadIdx.x;          // 512 threads
    const int lane = tid & 63;
    const int w    = tid >> 6;             // wave id 0..7

    __shared__ int s[LR_T];                // inclusive cumsum (ends)
    __shared__ int wsum[8];                // per-wave totals
    __shared__ int src16[FRAMES_PER_BLOCK];

    // --- scan ---
    int v = (int)floorf(dur[b * LR_T + tid] + 0.5f);
    #pragma unroll
    for (int off = 1; off < 64; off <<= 1) {
        int n = __shfl_up(v, off, 64);
        if (lane >= off) v += n;
    }
    if (lane == 63) wsum[w] = v;
    __syncthreads();
    if (tid < 8) {
        int t = wsum[tid];
        #pragma unroll
        for (int off = 1; off < 8; off <<= 1) {
            int n = __shfl_up(t, off, 8);
            if (tid >= off) t += n;
        }
        wsum[tid] = t;                     // inclusive wave-prefix
    }
    __syncthreads();
    s[tid] = v + (w > 0 ? wsum[w - 1] : 0);
    __syncthreads();

    const int total = s[LR_T - 1];

    // --- resolve this block's 16 frames ---
    if (tid < FRAMES_PER_BLOCK) {
        const int j = base + tid;
        int r = -1;
        if (j < total) {
            int lo = 0, hi = LR_T;         // first idx with s[idx] > j
            while (lo < hi) {
                int mid = (lo + hi) >> 1;
                if (s[mid] > j) hi = mid; else lo = mid + 1;
            }
            r = (lo < LR_T - 1) ? lo : (LR_T - 1);
        }
        src16[tid] = r;
    }
    __syncthreads();

    // --- copy: 4 passes x 4 frames, float4 per thread ---
    const int lane128 = tid & 127;         // float4 slot within a frame
    const int fgrp    = tid >> 7;          // 0..3: which frame this pass
    #pragma unroll
    for (int p = 0; p < 4; ++p) {
        const int fi = p * 4 + fgrp;
        const int si = src16[fi];
        float4 val = make_float4(0.f, 0.f, 0.f, 0.f);
        if (si >= 0) {
            const float4* row = (const float4*)(x + (size_t)(b * LR_T + si) * LR_D);
            val = row[lane128];
        }
        float4* orow = (float4*)(out + (size_t)(b * LR_TOUT + base + fi) * LR_D);
        orow[lane128] = val;
    }
}

extern "C" void kernel_launch(void* const* d_in, const int* in_sizes, int n_in,
                              void* d_out, int out_size, void* d_ws, size_t ws_size,
                              hipStream_t stream) {
    const float* x   = (const float*)d_in[0];   // [B, T, D] f32
    const float* dur = (const float*)d_in[1];   // [B, T]    f32
    float* out = (float*)d_out;                 // [B, T_OUT, D] f32

    dim3 grid(LR_TOUT / FRAMES_PER_BLOCK, LR_B);   // (160, 16)
    lr_fused_kernel<<<grid, 512, 0, stream>>>(x, dur, out);
}

// Round 5
// 101.127 us; speedup vs baseline: 1.1111x; 1.0066x over previous
//
#include <hip/hip_runtime.h>
#include <math.h>

// LengthRegulator: B=16, T=512, D=512, T_OUT=2560, all float32. Fully fused:
// ONE kernel, grid (T_OUT/16, B) x 512 threads (8 waves). Each block:
//   1. coalesced 2 KB dur load (L2-hot),
//   2. hybrid scan (wave shfl_up + 8-wave LDS combine) -> ends[] in LDS,
//      3 barriers total,
//   3. per-wave search: wave w owns frames 2w,2w+1; lanes 0-1 binary-search
//      ends[] (dependent LDS chain runs on 2 lanes, broadcast via __shfl) --
//      NO barrier after; waves retire independently (removes the R4
//      16-thread search bubble + 4th barrier),
//   4. per-wave copy: 2 frames x 2 float4/lane (full 2 KB row per frame).
// Zeros past total length. ~20 us kernel slice vs ~16 us BW floor; dur_us
// also carries ~75-80 us of harness re-poison/restore traffic (335 MB fill
// at 80% HBM peak visible in rocprof every iteration).

#define LR_B 16
#define LR_T 512
#define LR_D 512
#define LR_TOUT 2560
#define FRAMES_PER_BLOCK 16

__global__ __launch_bounds__(512) void lr_fused_kernel(
        const float* __restrict__ x,
        const float* __restrict__ dur,
        float* __restrict__ out) {
    const int b    = blockIdx.y;
    const int base = blockIdx.x * FRAMES_PER_BLOCK;
    const int tid  = threadIdx.x;          // 512 threads
    const int lane = tid & 63;
    const int w    = tid >> 6;             // wave id 0..7

    __shared__ int s[LR_T];                // inclusive cumsum (ends)
    __shared__ int wsum[8];                // per-wave totals

    // --- scan: wave-level shfl_up inclusive scan, then 8-wave combine ---
    int v = (int)floorf(dur[b * LR_T + tid] + 0.5f);
    #pragma unroll
    for (int off = 1; off < 64; off <<= 1) {
        int n = __shfl_up(v, off, 64);
        if (lane >= off) v += n;
    }
    if (lane == 63) wsum[w] = v;
    __syncthreads();
    if (tid < 8) {
        int t = wsum[tid];
        #pragma unroll
        for (int off = 1; off < 8; off <<= 1) {
            int n = __shfl_up(t, off, 8);
            if (tid >= off) t += n;
        }
        wsum[tid] = t;                     // inclusive wave-prefix
    }
    __syncthreads();
    s[tid] = v + (w > 0 ? wsum[w - 1] : 0);
    __syncthreads();

    const int total = s[LR_T - 1];

    // --- per-wave search: wave w owns frames 2w, 2w+1 ---
    // Lanes 0 and 1 each run one dependent binary-search chain; broadcast.
    int r = -1;
    if (lane < 2) {
        const int j = base + 2 * w + lane;
        if (j < total) {
            int lo = 0, hi = LR_T;         // first idx with s[idx] > j
            while (lo < hi) {
                int mid = (lo + hi) >> 1;
                if (s[mid] > j) hi = mid; else lo = mid + 1;
            }
            r = (lo < LR_T - 1) ? lo : (LR_T - 1);
        }
    }
    const int si0 = __shfl(r, 0, 64);
    const int si1 = __shfl(r, 1, 64);

    // --- per-wave copy: 2 frames, 2 float4 per lane per frame ---
    const size_t xb = (size_t)b * LR_T * LR_D;
    const size_t ob = (size_t)(b * LR_TOUT + base + 2 * w) * LR_D;

    float4 a0 = make_float4(0.f, 0.f, 0.f, 0.f), a1 = a0, b0 = a0, b1 = a0;
    if (si0 >= 0) {
        const float4* row = (const float4*)(x + xb + (size_t)si0 * LR_D);
        a0 = row[lane];
        a1 = row[lane + 64];
    }
    if (si1 >= 0) {
        const float4* row = (const float4*)(x + xb + (size_t)si1 * LR_D);
        b0 = row[lane];
        b1 = row[lane + 64];
    }
    float4* o0 = (float4*)(out + ob);
    float4* o1 = (float4*)(out + ob + LR_D);
    o0[lane]      = a0;
    o0[lane + 64] = a1;
    o1[lane]      = b0;
    o1[lane + 64] = b1;
}

extern "C" void kernel_launch(void* const* d_in, const int* in_sizes, int n_in,
                              void* d_out, int out_size, void* d_ws, size_t ws_size,
                              hipStream_t stream) {
    const float* x   = (const float*)d_in[0];   // [B, T, D] f32
    const float* dur = (const float*)d_in[1];   // [B, T]    f32
    float* out = (float*)d_out;                 // [B, T_OUT, D] f32

    dim3 grid(LR_TOUT / FRAMES_PER_BLOCK, LR_B);   // (160, 16)
    lr_fused_kernel<<<grid, 512, 0, stream>>>(x, dur, out);
}